// Round 3
// baseline (8647.915 us; speedup 1.0000x reference)
//
#include <hip/hip_runtime.h>
#include <hip/hip_bf16.h>
#include <math.h>

// Problem constants
#define SEQ   2048
#define VOC   50257
#define EMB   512
#define HID   768
#define G3    2304      // 3*HID
#define MDIM  256
#define CSZ   64
#define NCHUNK 32
#define UDIM  2048
#define E4    2048      // 4*EMB

#define G_GRU 48        // GRU workgroups; each owns 16 hidden units
#define CANARY 0xFFFFFFFFu   // -NaN bit pattern; GRU h is always finite => unreachable

typedef uint32_t u32x4  __attribute__((ext_vector_type(4)));
typedef float    f32x4  __attribute__((ext_vector_type(4)));
typedef short    s16x8  __attribute__((ext_vector_type(8)));   // 8 bf16 (4 VGPRs) - guide §3
typedef __bf16   bf16x8 __attribute__((ext_vector_type(8)));

// ---------------------------------------------------------------------------
// Embedding gather: X[s][e] = emb[ids[s]][e]
// ---------------------------------------------------------------------------
__global__ __launch_bounds__(256) void embed_kernel(const int* __restrict__ ids,
                                                    const float* __restrict__ emb,
                                                    float* __restrict__ X) {
    int s = blockIdx.x;
    int id = ids[s];
    const float* src = &emb[(size_t)id * EMB];
    float* dst = &X[(size_t)s * EMB];
    for (int i = threadIdx.x; i < EMB; i += 256) dst[i] = src[i];
}

// ---------------------------------------------------------------------------
// Generic fp32 GEMM:  C[M,N] = A[M,K] @ B[N,K]^T + bias[N]
// 128x128 tile, BK=16, 256 threads, 8x8 per thread. EPI 1 = relu^2.
// ---------------------------------------------------------------------------
template<int EPI>
__global__ __launch_bounds__(256) void gemm_nt(const float* __restrict__ A,
                                               const float* __restrict__ B,
                                               const float* __restrict__ bias,
                                               float* __restrict__ C,
                                               int M, int N, int K) {
    __shared__ float As[16][132];
    __shared__ float Bs[16][132];
    const int tid = threadIdx.x;
    const int tx = tid & 15;
    const int ty = tid >> 4;
    const int m0 = blockIdx.y * 128;
    const int n0 = blockIdx.x * 128;

    float acc[8][8];
    #pragma unroll
    for (int i = 0; i < 8; i++)
        #pragma unroll
        for (int j = 0; j < 8; j++) acc[i][j] = 0.f;

    for (int k0 = 0; k0 < K; k0 += 16) {
        #pragma unroll
        for (int i = 0; i < 2; i++) {
            int idx = tid * 2 + i;
            int r   = idx >> 2;
            int c4  = idx & 3;
            float4 av = {0.f, 0.f, 0.f, 0.f};
            float4 bv = {0.f, 0.f, 0.f, 0.f};
            int ar = m0 + r;
            if (ar < M) av = *reinterpret_cast<const float4*>(&A[(size_t)ar * K + k0 + c4 * 4]);
            int br = n0 + r;
            if (br < N) bv = *reinterpret_cast<const float4*>(&B[(size_t)br * K + k0 + c4 * 4]);
            As[c4 * 4 + 0][r] = av.x; As[c4 * 4 + 1][r] = av.y;
            As[c4 * 4 + 2][r] = av.z; As[c4 * 4 + 3][r] = av.w;
            Bs[c4 * 4 + 0][r] = bv.x; Bs[c4 * 4 + 1][r] = bv.y;
            Bs[c4 * 4 + 2][r] = bv.z; Bs[c4 * 4 + 3][r] = bv.w;
        }
        __syncthreads();
        #pragma unroll
        for (int k = 0; k < 16; k++) {
            float4 a0 = *reinterpret_cast<const float4*>(&As[k][ty * 4]);
            float4 a1 = *reinterpret_cast<const float4*>(&As[k][64 + ty * 4]);
            float4 b0 = *reinterpret_cast<const float4*>(&Bs[k][tx * 4]);
            float4 b1 = *reinterpret_cast<const float4*>(&Bs[k][64 + tx * 4]);
            float a[8] = {a0.x, a0.y, a0.z, a0.w, a1.x, a1.y, a1.z, a1.w};
            float b[8] = {b0.x, b0.y, b0.z, b0.w, b1.x, b1.y, b1.z, b1.w};
            #pragma unroll
            for (int i = 0; i < 8; i++)
                #pragma unroll
                for (int j = 0; j < 8; j++)
                    acc[i][j] = fmaf(a[i], b[j], acc[i][j]);
        }
        __syncthreads();
    }

    #pragma unroll
    for (int i = 0; i < 8; i++) {
        int r = m0 + ((i < 4) ? (ty * 4 + i) : (64 + ty * 4 + (i - 4)));
        if (r >= M) continue;
        #pragma unroll
        for (int j = 0; j < 8; j++) {
            int c = n0 + ((j < 4) ? (tx * 4 + j) : (64 + tx * 4 + (j - 4)));
            if (c >= N) continue;
            float v = acc[i][j] + bias[c];
            if (EPI == 1) { v = fmaxf(v, 0.f); v = v * v; }
            C[(size_t)r * N + c] = v;
        }
    }
}

// ---------------------------------------------------------------------------
// bf16 MFMA GEMM for base_logits: C[M,N] = A[M,K]fp32 @ B[N,K]fp32^T + bias.
// On-the-fly fp32->bf16 (v_cvt_pk via native casts). 128x128x32 tiles,
// 4 waves (2x2, 64x64 each), mfma_f32_16x16x32_bf16.
// LDS row stride 40 bf16 (80B): frag-read banks period-8 -> 2-way (free).
// ---------------------------------------------------------------------------
__global__ __launch_bounds__(256) void gemm_bf16_logits(const float* __restrict__ A,
                                                        const float* __restrict__ B,
                                                        const float* __restrict__ bias,
                                                        float* __restrict__ C,
                                                        int M, int N, int K) {
    constexpr int LDT = 40;
    __shared__ __bf16 As[128 * LDT];
    __shared__ __bf16 Bs[128 * LDT];
    const int tid  = threadIdx.x;
    const int lane = tid & 63;
    const int wave = tid >> 6;
    const int wm = wave >> 1;            // 0..1
    const int wn = wave & 1;             // 0..1
    const int m0 = blockIdx.y * 128;
    const int n0 = blockIdx.x * 128;
    const int l15 = lane & 15;
    const int l4  = lane >> 4;           // 0..3

    f32x4 acc[4][4];
    #pragma unroll
    for (int i = 0; i < 4; i++)
        #pragma unroll
        for (int j = 0; j < 4; j++) acc[i][j] = (f32x4){0.f, 0.f, 0.f, 0.f};

    const int r  = tid >> 1;             // 0..127 staged row
    const int hf = tid & 1;              // half of the 32-wide k slab

    for (int k0 = 0; k0 < K; k0 += 32) {
        const float* ap = &A[(size_t)(m0 + r) * K + k0 + hf * 16];
        float4 a0 = *reinterpret_cast<const float4*>(ap);
        float4 a1 = *reinterpret_cast<const float4*>(ap + 4);
        float4 a2 = *reinterpret_cast<const float4*>(ap + 8);
        float4 a3 = *reinterpret_cast<const float4*>(ap + 12);
        int bn = n0 + r;
        float4 b0 = {0,0,0,0}, b1 = {0,0,0,0}, b2 = {0,0,0,0}, b3 = {0,0,0,0};
        if (bn < N) {
            const float* bp = &B[(size_t)bn * K + k0 + hf * 16];
            b0 = *reinterpret_cast<const float4*>(bp);
            b1 = *reinterpret_cast<const float4*>(bp + 4);
            b2 = *reinterpret_cast<const float4*>(bp + 8);
            b3 = *reinterpret_cast<const float4*>(bp + 12);
        }
        __syncthreads();   // previous tile fully consumed
        {
            __bf16* da = &As[r * LDT + hf * 16];
            bf16x8 w0, w1;
            w0[0]=(__bf16)a0.x; w0[1]=(__bf16)a0.y; w0[2]=(__bf16)a0.z; w0[3]=(__bf16)a0.w;
            w0[4]=(__bf16)a1.x; w0[5]=(__bf16)a1.y; w0[6]=(__bf16)a1.z; w0[7]=(__bf16)a1.w;
            w1[0]=(__bf16)a2.x; w1[1]=(__bf16)a2.y; w1[2]=(__bf16)a2.z; w1[3]=(__bf16)a2.w;
            w1[4]=(__bf16)a3.x; w1[5]=(__bf16)a3.y; w1[6]=(__bf16)a3.z; w1[7]=(__bf16)a3.w;
            *reinterpret_cast<bf16x8*>(da)     = w0;
            *reinterpret_cast<bf16x8*>(da + 8) = w1;
            __bf16* db = &Bs[r * LDT + hf * 16];
            bf16x8 v0, v1;
            v0[0]=(__bf16)b0.x; v0[1]=(__bf16)b0.y; v0[2]=(__bf16)b0.z; v0[3]=(__bf16)b0.w;
            v0[4]=(__bf16)b1.x; v0[5]=(__bf16)b1.y; v0[6]=(__bf16)b1.z; v0[7]=(__bf16)b1.w;
            v1[0]=(__bf16)b2.x; v1[1]=(__bf16)b2.y; v1[2]=(__bf16)b2.z; v1[3]=(__bf16)b2.w;
            v1[4]=(__bf16)b3.x; v1[5]=(__bf16)b3.y; v1[6]=(__bf16)b3.z; v1[7]=(__bf16)b3.w;
            *reinterpret_cast<bf16x8*>(db)     = v0;
            *reinterpret_cast<bf16x8*>(db + 8) = v1;
        }
        __syncthreads();

        s16x8 af[4], bf[4];
        #pragma unroll
        for (int i = 0; i < 4; i++)
            af[i] = *reinterpret_cast<const s16x8*>(&As[(wm * 64 + i * 16 + l15) * LDT + l4 * 8]);
        #pragma unroll
        for (int j = 0; j < 4; j++)
            bf[j] = *reinterpret_cast<const s16x8*>(&Bs[(wn * 64 + j * 16 + l15) * LDT + l4 * 8]);
        #pragma unroll
        for (int i = 0; i < 4; i++)
            #pragma unroll
            for (int j = 0; j < 4; j++)
                acc[i][j] = __builtin_amdgcn_mfma_f32_16x16x32_bf16(af[i], bf[j], acc[i][j], 0, 0, 0);
    }

    #pragma unroll
    for (int j = 0; j < 4; j++) {
        int col = n0 + wn * 64 + j * 16 + l15;
        if (col >= N) continue;
        float bv = bias[col];
        #pragma unroll
        for (int i = 0; i < 4; i++) {
            int row = m0 + wm * 64 + i * 16 + l4 * 4;
            #pragma unroll
            for (int q = 0; q < 4; q++)
                C[(size_t)(row + q) * N + col] = acc[i][j][q] + bv;
        }
    }
}

// ---------------------------------------------------------------------------
// GRU v3: zero-LDS, zero-barrier persistent kernel. 48 WGs x 256 threads.
// Each thread polls exactly the 48 h-words it consumes (12 x dwordx4, one asm
// block incl. vmcnt(0)), detects arrival via NaN-propagation over the canary.
// Publish: agent-scope relaxed atomic store (proven cross-XCD visible in v2).
// No __syncthreads in the loop; shfl butterfly is wave-synchronous.
// ---------------------------------------------------------------------------
__device__ __forceinline__ float fast_sigmoid(float x) {
    x = fminf(fmaxf(x, -30.f), 30.f);
    return __builtin_amdgcn_rcpf(1.f + __expf(-x));
}
__device__ __forceinline__ float fast_tanh(float x) {
    x = fminf(fmaxf(x, -15.f), 15.f);
    float e = __expf(2.f * x);
    return (e - 1.f) * __builtin_amdgcn_rcpf(e + 1.f);
}

__global__ __launch_bounds__(256, 1) void gru_kernel(const float* __restrict__ GX,
                                                     const float* __restrict__ Whh,
                                                     const float* __restrict__ bhh,
                                                     float* __restrict__ states) {
    const int tid = threadIdx.x;
    const int g   = blockIdx.x;          // 0..47
    const int tx  = tid & 15;
    const int ty  = tid >> 4;
    const int gu  = g * 16 + ty;

    // W_hh rows into registers (one-time): 3 gates x 48 floats
    float4 W4[3][12];
    #pragma unroll
    for (int p = 0; p < 3; p++) {
        const float* wr = &Whh[(size_t)(p * HID + gu) * HID + 4 * tx];
        #pragma unroll
        for (int j = 0; j < 12; j++)
            W4[p][j] = *reinterpret_cast<const float4*>(&wr[64 * j]);
    }
    float bh[3];
    #pragma unroll
    for (int p = 0; p < 3; p++) bh[p] = bhh[p * HID + gu];

    float hv  = 0.f;
    float gx0 = GX[0 * HID + gu];
    float gx1 = GX[1 * HID + gu];
    float gx2 = GX[2 * HID + gu];

    for (int t = 0; t < SEQ; t++) {
        // prefetch next step's gx (issues before the poll; hides under spin)
        float ngx0 = 0.f, ngx1 = 0.f, ngx2 = 0.f;
        if (t + 1 < SEQ) {
            const float* gp = &GX[(size_t)(t + 1) * G3];
            ngx0 = gp[0 * HID + gu];
            ngx1 = gp[1 * HID + gu];
            ngx2 = gp[2 * HID + gu];
        }

        f32x4 h[12];
        if (t > 0) {
            const uint32_t* pp = (const uint32_t*)(states + (size_t)(t - 1) * HID + 4 * tx);
            u32x4 q0,q1,q2,q3,q4,q5,q6,q7,q8,q9,q10,q11;
            float s;
            do {
                asm volatile(
                    "global_load_dwordx4 %0, %12, off sc0 sc1\n\t"
                    "global_load_dwordx4 %1, %12, off offset:256 sc0 sc1\n\t"
                    "global_load_dwordx4 %2, %12, off offset:512 sc0 sc1\n\t"
                    "global_load_dwordx4 %3, %12, off offset:768 sc0 sc1\n\t"
                    "global_load_dwordx4 %4, %12, off offset:1024 sc0 sc1\n\t"
                    "global_load_dwordx4 %5, %12, off offset:1280 sc0 sc1\n\t"
                    "global_load_dwordx4 %6, %12, off offset:1536 sc0 sc1\n\t"
                    "global_load_dwordx4 %7, %12, off offset:1792 sc0 sc1\n\t"
                    "global_load_dwordx4 %8, %12, off offset:2048 sc0 sc1\n\t"
                    "global_load_dwordx4 %9, %12, off offset:2304 sc0 sc1\n\t"
                    "global_load_dwordx4 %10, %12, off offset:2560 sc0 sc1\n\t"
                    "global_load_dwordx4 %11, %12, off offset:2816 sc0 sc1\n\t"
                    "s_waitcnt vmcnt(0)"
                    : "=&v"(q0), "=&v"(q1), "=&v"(q2), "=&v"(q3), "=&v"(q4), "=&v"(q5),
                      "=&v"(q6), "=&v"(q7), "=&v"(q8), "=&v"(q9), "=&v"(q10), "=&v"(q11)
                    : "v"(pp)
                    : "memory");
                h[0]  = __builtin_bit_cast(f32x4, q0);
                h[1]  = __builtin_bit_cast(f32x4, q1);
                h[2]  = __builtin_bit_cast(f32x4, q2);
                h[3]  = __builtin_bit_cast(f32x4, q3);
                h[4]  = __builtin_bit_cast(f32x4, q4);
                h[5]  = __builtin_bit_cast(f32x4, q5);
                h[6]  = __builtin_bit_cast(f32x4, q6);
                h[7]  = __builtin_bit_cast(f32x4, q7);
                h[8]  = __builtin_bit_cast(f32x4, q8);
                h[9]  = __builtin_bit_cast(f32x4, q9);
                h[10] = __builtin_bit_cast(f32x4, q10);
                h[11] = __builtin_bit_cast(f32x4, q11);
                s = 0.f;
                #pragma unroll
                for (int j = 0; j < 12; j++) s += h[j][0] + h[j][1] + h[j][2] + h[j][3];
            } while (s != s);   // NaN iff any word still canary
        } else {
            #pragma unroll
            for (int j = 0; j < 12; j++) h[j] = (f32x4){0.f, 0.f, 0.f, 0.f};
        }

        // matvec: 3 owned rows x this thread's 48-wide slice
        float accp[3];
        #pragma unroll
        for (int p = 0; p < 3; p++) {
            float a = 0.f;
            #pragma unroll
            for (int j = 0; j < 12; j++) {
                a = fmaf(W4[p][j].x, h[j][0], a);
                a = fmaf(W4[p][j].y, h[j][1], a);
                a = fmaf(W4[p][j].z, h[j][2], a);
                a = fmaf(W4[p][j].w, h[j][3], a);
            }
            accp[p] = a;
        }
        #pragma unroll
        for (int p = 0; p < 3; p++) {
            accp[p] += __shfl_xor(accp[p], 1);
            accp[p] += __shfl_xor(accp[p], 2);
            accp[p] += __shfl_xor(accp[p], 4);
            accp[p] += __shfl_xor(accp[p], 8);
        }

        float r = fast_sigmoid(gx0 + accp[0] + bh[0]);
        float z = fast_sigmoid(gx1 + accp[1] + bh[1]);
        float n = fast_tanh(gx2 + accp[2] + r * (accp[2] * 0.f + accp[2]) * 0.f + accp[2] * 0.f + r * (accp[2] + bh[2]) - accp[2] + 0.f * bh[2]);
        // NOTE: expression above must equal tanh(gx2 + r*(hn)) with hn = accp[2]+bh[2];
        n = fast_tanh(gx2 + r * (accp[2] + bh[2]));
        hv = (1.f - z) * n + z * hv;

        if (tx == 0)
            __hip_atomic_store((uint32_t*)&states[(size_t)t * HID + gu],
                               __float_as_uint(hv),
                               __ATOMIC_RELAXED, __HIP_MEMORY_SCOPE_AGENT);
        gx0 = ngx0; gx1 = ngx1; gx2 = ngx2;
    }
}

// ---------------------------------------------------------------------------
// chunked[c][e] = mean over 64 steps
// ---------------------------------------------------------------------------
__global__ __launch_bounds__(256) void chunkmean_kernel(const float* __restrict__ states,
                                                        float* __restrict__ chunked) {
    int c = blockIdx.x;
    for (int e = threadIdx.x; e < HID; e += 256) {
        float s = 0.f;
        #pragma unroll 8
        for (int i = 0; i < CSZ; i++)
            s += states[(size_t)(c * CSZ + i) * HID + e];
        chunked[c * HID + e] = s * (1.f / 64.f);
    }
}

// ---------------------------------------------------------------------------
// attention weights
// ---------------------------------------------------------------------------
__global__ void attn_kernel(const float* __restrict__ qk,
                            const float* __restrict__ mk,
                            float* __restrict__ attn) {
    int s = blockIdx.x;
    int lane = threadIdx.x;      // 64 threads
    int c = lane & 31;
    int h = lane >> 5;
    const float* q = &qk[(size_t)s * MDIM];
    const float* m = &mk[(size_t)c * MDIM];
    float sc = 0.f;
    for (int k = h; k < MDIM; k += 2) sc = fmaf(q[k], m[k], sc);
    sc += __shfl_xor(sc, 32);
    sc *= (1.0f / 16.0f);
    bool allowed = (CSZ * c + (CSZ - 1)) < s;
    float v = allowed ? sc : -3.4e38f;
    float mx = v;
    #pragma unroll
    for (int d = 16; d >= 1; d >>= 1) mx = fmaxf(mx, __shfl_xor(mx, d));
    float e = (allowed && mx > -1e37f) ? expf(sc - mx) : 0.f;
    float sm = e;
    #pragma unroll
    for (int d = 16; d >= 1; d >>= 1) sm += __shfl_xor(sm, d);
    float a = (sm > 0.f) ? e / sm : 0.f;
    if (lane < 32) attn[(size_t)s * NCHUNK + c] = a;
}

// ---------------------------------------------------------------------------
// total_partial = base_partial + attn @ chunk_partial; scatter-add into out
// ---------------------------------------------------------------------------
__global__ __launch_bounds__(256) void total_scatter_kernel(const float* __restrict__ bp,
                                                            const float* __restrict__ cp,
                                                            const float* __restrict__ attn,
                                                            const int* __restrict__ uids,
                                                            float* __restrict__ out) {
    int s = blockIdx.x;
    __shared__ float a_s[NCHUNK];
    if (threadIdx.x < NCHUNK) a_s[threadIdx.x] = attn[(size_t)s * NCHUNK + threadIdx.x];
    __syncthreads();
    for (int u = threadIdx.x; u < UDIM; u += 256) {
        float t = bp[(size_t)s * UDIM + u];
        #pragma unroll 8
        for (int c = 0; c < NCHUNK; c++)
            t = fmaf(a_s[c], cp[(size_t)c * UDIM + u], t);
        atomicAdd(&out[(size_t)s * VOC + uids[u]], t);
    }
}

// ---------------------------------------------------------------------------
// launch
// ---------------------------------------------------------------------------
extern "C" void kernel_launch(void* const* d_in, const int* in_sizes, int n_in,
                              void* d_out, int out_size, void* d_ws, size_t ws_size,
                              hipStream_t stream) {
    const int*   ids   = (const int*)d_in[0];
    const int*   uids  = (const int*)d_in[1];
    const float* emb   = (const float*)d_in[2];
    const float* w_ih  = (const float*)d_in[3];
    const float* w_hh  = (const float*)d_in[4];
    const float* b_ih  = (const float*)d_in[5];
    const float* b_hh  = (const float*)d_in[6];
    const float* Wq    = (const float*)d_in[7];
    const float* bq    = (const float*)d_in[8];
    const float* Wk    = (const float*)d_in[9];
    const float* bk    = (const float*)d_in[10];
    const float* Whf   = (const float*)d_in[11];
    const float* bhf   = (const float*)d_in[12];
    const float* Whp   = (const float*)d_in[13];
    const float* bhp   = (const float*)d_in[14];
    const float* Wcv   = (const float*)d_in[15];
    const float* bcv   = (const float*)d_in[16];
    const float* Wph   = (const float*)d_in[17];
    const float* bph   = (const float*)d_in[18];
    const float* obias = (const float*)d_in[19];
    float* out = (float*)d_out;
    float* wsf = (float*)d_ws;

    // workspace layout (floats)
    size_t off = 0;
    float* X      = wsf + off; off += (size_t)SEQ * EMB;
    float* GX     = wsf + off; off += (size_t)SEQ * G3;
    float* states = wsf + off; off += (size_t)SEQ * HID;
    float* head   = wsf + off; off += (size_t)SEQ * E4;
    float* bfeat  = wsf + off; off += (size_t)SEQ * EMB;
    float* chunk  = wsf + off; off += (size_t)NCHUNK * HID;
    float* qk     = wsf + off; off += (size_t)SEQ * MDIM;
    float* mk     = wsf + off; off += (size_t)NCHUNK * MDIM;
    float* cv     = wsf + off; off += (size_t)NCHUNK * EMB;
    float* cp     = wsf + off; off += (size_t)NCHUNK * UDIM;
    float* bp     = wsf + off; off += (size_t)SEQ * UDIM;
    float* attn   = wsf + off; off += (size_t)SEQ * NCHUNK;

    // 1) embedding gather; canary-fill states early (off critical path)
    embed_kernel<<<SEQ, 256, 0, stream>>>(ids, emb, X);
    hipMemsetAsync(states, 0xFF, (size_t)SEQ * HID * sizeof(float), stream);
    // 2) GX = X @ w_ih^T + b_ih
    gemm_nt<0><<<dim3(G3 / 128, SEQ / 128), 256, 0, stream>>>(X, w_ih, b_ih, GX, SEQ, G3, EMB);
    // 3) persistent GRU
    gru_kernel<<<G_GRU, 256, 0, stream>>>(GX, w_hh, b_hh, states);
    // 4) chunk means
    chunkmean_kernel<<<NCHUNK, 256, 0, stream>>>(states, chunk);
    // 5) projections (fp32)
    gemm_nt<0><<<dim3(MDIM / 128, SEQ / 128), 256, 0, stream>>>(states, Wq, bq, qk, SEQ, MDIM, HID);
    gemm_nt<0><<<dim3(MDIM / 128, 1), 256, 0, stream>>>(chunk, Wk, bk, mk, NCHUNK, MDIM, HID);
    gemm_nt<1><<<dim3(E4 / 128, SEQ / 128), 256, 0, stream>>>(states, Whf, bhf, head, SEQ, E4, HID);
    gemm_nt<0><<<dim3(EMB / 128, SEQ / 128), 256, 0, stream>>>(head, Whp, bhp, bfeat, SEQ, EMB, E4);
    gemm_nt<0><<<dim3(EMB / 128, 1), 256, 0, stream>>>(chunk, Wcv, bcv, cv, NCHUNK, EMB, HID);
    gemm_nt<0><<<dim3(UDIM / 128, 1), 256, 0, stream>>>(cv, Wph, bph, cp, NCHUNK, UDIM, EMB);
    gemm_nt<0><<<dim3(UDIM / 128, SEQ / 128), 256, 0, stream>>>(bfeat, Wph, bph, bp, SEQ, UDIM, EMB);
    // 6) base_logits (bf16 MFMA) -> d_out
    gemm_bf16_logits<<<dim3((VOC + 127) / 128, SEQ / 128), 256, 0, stream>>>(bfeat, emb, obias, out, SEQ, VOC, EMB);
    // 7) attention weights
    attn_kernel<<<SEQ, 64, 0, stream>>>(qk, mk, attn);
    // 8) total partial + scatter-add
    total_scatter_kernel<<<SEQ, 256, 0, stream>>>(bp, cp, attn, uids, out);
}

// Round 4
// 5744.319 us; speedup vs baseline: 1.5055x; 1.5055x over previous
//
#include <hip/hip_runtime.h>
#include <hip/hip_bf16.h>
#include <math.h>

// Problem constants
#define SEQ   2048
#define VOC   50257
#define EMB   512
#define HID   768
#define G3    2304      // 3*HID
#define MDIM  256
#define CSZ   64
#define NCHUNK 32
#define UDIM  2048
#define E4    2048      // 4*EMB

#define G_GRU 48        // GRU workgroups; each owns 16 hidden units
#define CANARY 0xFFFFFFFFu   // -NaN bit pattern; GRU h is always finite => unreachable

typedef uint32_t u32x4  __attribute__((ext_vector_type(4)));
typedef float    f32x4  __attribute__((ext_vector_type(4)));
typedef short    s16x8  __attribute__((ext_vector_type(8)));   // 8 bf16 (4 VGPRs)
typedef __bf16   bf16x8 __attribute__((ext_vector_type(8)));

// ---------------------------------------------------------------------------
// Embedding gather: X[s][e] = emb[ids[s]][e]
// ---------------------------------------------------------------------------
__global__ __launch_bounds__(256) void embed_kernel(const int* __restrict__ ids,
                                                    const float* __restrict__ emb,
                                                    float* __restrict__ X) {
    int s = blockIdx.x;
    int id = ids[s];
    const float* src = &emb[(size_t)id * EMB];
    float* dst = &X[(size_t)s * EMB];
    for (int i = threadIdx.x; i < EMB; i += 256) dst[i] = src[i];
}

// ---------------------------------------------------------------------------
// Generic fp32 GEMM:  C[M,N] = A[M,K] @ B[N,K]^T + bias[N]
// 128x128 tile, BK=16, 256 threads, 8x8 per thread. EPI 1 = relu^2.
// ---------------------------------------------------------------------------
template<int EPI>
__global__ __launch_bounds__(256) void gemm_nt(const float* __restrict__ A,
                                               const float* __restrict__ B,
                                               const float* __restrict__ bias,
                                               float* __restrict__ C,
                                               int M, int N, int K) {
    __shared__ float As[16][132];
    __shared__ float Bs[16][132];
    const int tid = threadIdx.x;
    const int tx = tid & 15;
    const int ty = tid >> 4;
    const int m0 = blockIdx.y * 128;
    const int n0 = blockIdx.x * 128;

    float acc[8][8];
    #pragma unroll
    for (int i = 0; i < 8; i++)
        #pragma unroll
        for (int j = 0; j < 8; j++) acc[i][j] = 0.f;

    for (int k0 = 0; k0 < K; k0 += 16) {
        #pragma unroll
        for (int i = 0; i < 2; i++) {
            int idx = tid * 2 + i;
            int r   = idx >> 2;
            int c4  = idx & 3;
            float4 av = {0.f, 0.f, 0.f, 0.f};
            float4 bv = {0.f, 0.f, 0.f, 0.f};
            int ar = m0 + r;
            if (ar < M) av = *reinterpret_cast<const float4*>(&A[(size_t)ar * K + k0 + c4 * 4]);
            int br = n0 + r;
            if (br < N) bv = *reinterpret_cast<const float4*>(&B[(size_t)br * K + k0 + c4 * 4]);
            As[c4 * 4 + 0][r] = av.x; As[c4 * 4 + 1][r] = av.y;
            As[c4 * 4 + 2][r] = av.z; As[c4 * 4 + 3][r] = av.w;
            Bs[c4 * 4 + 0][r] = bv.x; Bs[c4 * 4 + 1][r] = bv.y;
            Bs[c4 * 4 + 2][r] = bv.z; Bs[c4 * 4 + 3][r] = bv.w;
        }
        __syncthreads();
        #pragma unroll
        for (int k = 0; k < 16; k++) {
            float4 a0 = *reinterpret_cast<const float4*>(&As[k][ty * 4]);
            float4 a1 = *reinterpret_cast<const float4*>(&As[k][64 + ty * 4]);
            float4 b0 = *reinterpret_cast<const float4*>(&Bs[k][tx * 4]);
            float4 b1 = *reinterpret_cast<const float4*>(&Bs[k][64 + tx * 4]);
            float a[8] = {a0.x, a0.y, a0.z, a0.w, a1.x, a1.y, a1.z, a1.w};
            float b[8] = {b0.x, b0.y, b0.z, b0.w, b1.x, b1.y, b1.z, b1.w};
            #pragma unroll
            for (int i = 0; i < 8; i++)
                #pragma unroll
                for (int j = 0; j < 8; j++)
                    acc[i][j] = fmaf(a[i], b[j], acc[i][j]);
        }
        __syncthreads();
    }

    #pragma unroll
    for (int i = 0; i < 8; i++) {
        int r = m0 + ((i < 4) ? (ty * 4 + i) : (64 + ty * 4 + (i - 4)));
        if (r >= M) continue;
        #pragma unroll
        for (int j = 0; j < 8; j++) {
            int c = n0 + ((j < 4) ? (tx * 4 + j) : (64 + tx * 4 + (j - 4)));
            if (c >= N) continue;
            float v = acc[i][j] + bias[c];
            if (EPI == 1) { v = fmaxf(v, 0.f); v = v * v; }
            C[(size_t)r * N + c] = v;
        }
    }
}

// ---------------------------------------------------------------------------
// bf16 MFMA GEMM for base_logits (unchanged from round 3; verified).
// ---------------------------------------------------------------------------
__global__ __launch_bounds__(256) void gemm_bf16_logits(const float* __restrict__ A,
                                                        const float* __restrict__ B,
                                                        const float* __restrict__ bias,
                                                        float* __restrict__ C,
                                                        int M, int N, int K) {
    constexpr int LDT = 40;
    __shared__ __bf16 As[128 * LDT];
    __shared__ __bf16 Bs[128 * LDT];
    const int tid  = threadIdx.x;
    const int lane = tid & 63;
    const int wave = tid >> 6;
    const int wm = wave >> 1;
    const int wn = wave & 1;
    const int m0 = blockIdx.y * 128;
    const int n0 = blockIdx.x * 128;
    const int l15 = lane & 15;
    const int l4  = lane >> 4;

    f32x4 acc[4][4];
    #pragma unroll
    for (int i = 0; i < 4; i++)
        #pragma unroll
        for (int j = 0; j < 4; j++) acc[i][j] = (f32x4){0.f, 0.f, 0.f, 0.f};

    const int r  = tid >> 1;
    const int hf = tid & 1;

    for (int k0 = 0; k0 < K; k0 += 32) {
        const float* ap = &A[(size_t)(m0 + r) * K + k0 + hf * 16];
        float4 a0 = *reinterpret_cast<const float4*>(ap);
        float4 a1 = *reinterpret_cast<const float4*>(ap + 4);
        float4 a2 = *reinterpret_cast<const float4*>(ap + 8);
        float4 a3 = *reinterpret_cast<const float4*>(ap + 12);
        int bn = n0 + r;
        float4 b0 = {0,0,0,0}, b1 = {0,0,0,0}, b2 = {0,0,0,0}, b3 = {0,0,0,0};
        if (bn < N) {
            const float* bp = &B[(size_t)bn * K + k0 + hf * 16];
            b0 = *reinterpret_cast<const float4*>(bp);
            b1 = *reinterpret_cast<const float4*>(bp + 4);
            b2 = *reinterpret_cast<const float4*>(bp + 8);
            b3 = *reinterpret_cast<const float4*>(bp + 12);
        }
        __syncthreads();
        {
            __bf16* da = &As[r * LDT + hf * 16];
            bf16x8 w0, w1;
            w0[0]=(__bf16)a0.x; w0[1]=(__bf16)a0.y; w0[2]=(__bf16)a0.z; w0[3]=(__bf16)a0.w;
            w0[4]=(__bf16)a1.x; w0[5]=(__bf16)a1.y; w0[6]=(__bf16)a1.z; w0[7]=(__bf16)a1.w;
            w1[0]=(__bf16)a2.x; w1[1]=(__bf16)a2.y; w1[2]=(__bf16)a2.z; w1[3]=(__bf16)a2.w;
            w1[4]=(__bf16)a3.x; w1[5]=(__bf16)a3.y; w1[6]=(__bf16)a3.z; w1[7]=(__bf16)a3.w;
            *reinterpret_cast<bf16x8*>(da)     = w0;
            *reinterpret_cast<bf16x8*>(da + 8) = w1;
            __bf16* db = &Bs[r * LDT + hf * 16];
            bf16x8 v0, v1;
            v0[0]=(__bf16)b0.x; v0[1]=(__bf16)b0.y; v0[2]=(__bf16)b0.z; v0[3]=(__bf16)b0.w;
            v0[4]=(__bf16)b1.x; v0[5]=(__bf16)b1.y; v0[6]=(__bf16)b1.z; v0[7]=(__bf16)b1.w;
            v1[0]=(__bf16)b2.x; v1[1]=(__bf16)b2.y; v1[2]=(__bf16)b2.z; v1[3]=(__bf16)b2.w;
            v1[4]=(__bf16)b3.x; v1[5]=(__bf16)b3.y; v1[6]=(__bf16)b3.z; v1[7]=(__bf16)b3.w;
            *reinterpret_cast<bf16x8*>(db)     = v0;
            *reinterpret_cast<bf16x8*>(db + 8) = v1;
        }
        __syncthreads();

        s16x8 af[4], bf[4];
        #pragma unroll
        for (int i = 0; i < 4; i++)
            af[i] = *reinterpret_cast<const s16x8*>(&As[(wm * 64 + i * 16 + l15) * LDT + l4 * 8]);
        #pragma unroll
        for (int j = 0; j < 4; j++)
            bf[j] = *reinterpret_cast<const s16x8*>(&Bs[(wn * 64 + j * 16 + l15) * LDT + l4 * 8]);
        #pragma unroll
        for (int i = 0; i < 4; i++)
            #pragma unroll
            for (int j = 0; j < 4; j++)
                acc[i][j] = __builtin_amdgcn_mfma_f32_16x16x32_bf16(af[i], bf[j], acc[i][j], 0, 0, 0);
    }

    #pragma unroll
    for (int j = 0; j < 4; j++) {
        int col = n0 + wn * 64 + j * 16 + l15;
        if (col >= N) continue;
        float bv = bias[col];
        #pragma unroll
        for (int i = 0; i < 4; i++) {
            int row = m0 + wm * 64 + i * 16 + l4 * 4;
            #pragma unroll
            for (int q = 0; q < 4; q++)
                C[(size_t)(row + q) * N + col] = acc[i][j][q] + bv;
        }
    }
}

// ---------------------------------------------------------------------------
// GRU v4: v2's proven rendezvous (unique-word poll + LDS share + 1 barrier)
// with a thinner critical path:
//  - poll: 192 threads each poll ONE 16B chunk (1 dwordx4 sc0 sc1 per retry)
//  - publish: each wave shfl-collects its 4 units' hv and lane 0 issues ONE
//    16B store (4 stores/WG vs 16 scattered dwords) -> chunk-atomic arrival
//  - fast gates (__expf + rcp, clamped)
// Race-freedom: publish of step t follows all of the WG's h_s reads of step
// t-1 (read -> fma -> publish program order per wave; detection of step t
// requires all waves' publishes), so overwriting h_s after detection is safe.
// ---------------------------------------------------------------------------
__device__ __forceinline__ float fast_sigmoid(float x) {
    x = fminf(fmaxf(x, -30.f), 30.f);
    return __builtin_amdgcn_rcpf(1.f + __expf(-x));
}
__device__ __forceinline__ float fast_tanh(float x) {
    x = fminf(fmaxf(x, -15.f), 15.f);
    float e = __expf(2.f * x);
    return (e - 1.f) * __builtin_amdgcn_rcpf(e + 1.f);
}

__global__ __launch_bounds__(256, 1) void gru_kernel(const float* __restrict__ GX,
                                                     const float* __restrict__ Whh,
                                                     const float* __restrict__ bhh,
                                                     float* __restrict__ states) {
    __shared__ float h_s[HID];
    const int tid  = threadIdx.x;
    const int g    = blockIdx.x;          // 0..47
    const int tx   = tid & 15;
    const int ty   = tid >> 4;
    const int gu   = g * 16 + ty;
    const int wave = tid >> 6;            // 0..3
    const int lane = tid & 63;

    // W_hh rows into registers (one-time): 3 gates x 48 floats
    float4 W4[3][12];
    #pragma unroll
    for (int p = 0; p < 3; p++) {
        const float* wr = &Whh[(size_t)(p * HID + gu) * HID + 4 * tx];
        #pragma unroll
        for (int j = 0; j < 12; j++)
            W4[p][j] = *reinterpret_cast<const float4*>(&wr[64 * j]);
    }
    float bh[3];
    #pragma unroll
    for (int p = 0; p < 3; p++) bh[p] = bhh[p * HID + gu];

    float hv  = 0.f;
    float gx0 = GX[0 * HID + gu];
    float gx1 = GX[1 * HID + gu];
    float gx2 = GX[2 * HID + gu];

    for (int t = 0; t < SEQ; t++) {
        // prefetch next step's gx (issues before the poll; hides under spin)
        float ngx0 = 0.f, ngx1 = 0.f, ngx2 = 0.f;
        if (t + 1 < SEQ) {
            const float* gp = &GX[(size_t)(t + 1) * G3];
            ngx0 = gp[0 * HID + gu];
            ngx1 = gp[1 * HID + gu];
            ngx2 = gp[2 * HID + gu];
        }

        float4 h4[12];
        if (t > 0) {
            if (tid < 192) {
                // poll this thread's unique 16B chunk of h_{t-1}
                const float* pp = states + (size_t)(t - 1) * HID + tid * 4;
                u32x4 q;
                float s;
                do {
                    asm volatile(
                        "global_load_dwordx4 %0, %1, off sc0 sc1\n\t"
                        "s_waitcnt vmcnt(0)"
                        : "=&v"(q) : "v"(pp) : "memory");
                    f32x4 f = __builtin_bit_cast(f32x4, q);
                    s = f[0] + f[1] + f[2] + f[3];
                } while (s != s);   // NaN iff any word still canary
                *reinterpret_cast<u32x4*>(&h_s[tid * 4]) = q;
            }
            __syncthreads();
            #pragma unroll
            for (int j = 0; j < 12; j++)
                h4[j] = *reinterpret_cast<const float4*>(&h_s[4 * tx + 64 * j]);
        } else {
            #pragma unroll
            for (int j = 0; j < 12; j++) h4[j] = make_float4(0.f, 0.f, 0.f, 0.f);
        }

        // matvec: 3 owned rows x this thread's 48-wide slice
        float accp[3];
        #pragma unroll
        for (int p = 0; p < 3; p++) {
            float a = 0.f;
            #pragma unroll
            for (int j = 0; j < 12; j++) {
                a = fmaf(W4[p][j].x, h4[j].x, a);
                a = fmaf(W4[p][j].y, h4[j].y, a);
                a = fmaf(W4[p][j].z, h4[j].z, a);
                a = fmaf(W4[p][j].w, h4[j].w, a);
            }
            accp[p] = a;
        }
        #pragma unroll
        for (int p = 0; p < 3; p++) {
            accp[p] += __shfl_xor(accp[p], 1);
            accp[p] += __shfl_xor(accp[p], 2);
            accp[p] += __shfl_xor(accp[p], 4);
            accp[p] += __shfl_xor(accp[p], 8);
        }

        // gates (all lanes of a unit-group compute identical hv)
        float r = fast_sigmoid(gx0 + accp[0] + bh[0]);
        float z = fast_sigmoid(gx1 + accp[1] + bh[1]);
        float n = fast_tanh(gx2 + r * (accp[2] + bh[2]));
        hv = (1.f - z) * n + z * hv;

        // publish: wave w holds units 4w..4w+3 (hv at lanes 16k); collect to
        // lane 0 and issue ONE 16B store per wave.
        float v0 = __shfl(hv, 0);
        float v1 = __shfl(hv, 16);
        float v2 = __shfl(hv, 32);
        float v3 = __shfl(hv, 48);
        if (lane == 0) {
            f32x4 pv = {v0, v1, v2, v3};
            float* dp = states + (size_t)t * HID + g * 16 + wave * 4;
            asm volatile(
                "global_store_dwordx4 %0, %1, off sc0 sc1"
                :: "v"(dp), "v"(pv) : "memory");
        }
        gx0 = ngx0; gx1 = ngx1; gx2 = ngx2;
    }
}

// ---------------------------------------------------------------------------
// chunked[c][e] = mean over 64 steps
// ---------------------------------------------------------------------------
__global__ __launch_bounds__(256) void chunkmean_kernel(const float* __restrict__ states,
                                                        float* __restrict__ chunked) {
    int c = blockIdx.x;
    for (int e = threadIdx.x; e < HID; e += 256) {
        float s = 0.f;
        #pragma unroll 8
        for (int i = 0; i < CSZ; i++)
            s += states[(size_t)(c * CSZ + i) * HID + e];
        chunked[c * HID + e] = s * (1.f / 64.f);
    }
}

// ---------------------------------------------------------------------------
// attention weights
// ---------------------------------------------------------------------------
__global__ void attn_kernel(const float* __restrict__ qk,
                            const float* __restrict__ mk,
                            float* __restrict__ attn) {
    int s = blockIdx.x;
    int lane = threadIdx.x;      // 64 threads
    int c = lane & 31;
    int h = lane >> 5;
    const float* q = &qk[(size_t)s * MDIM];
    const float* m = &mk[(size_t)c * MDIM];
    float sc = 0.f;
    for (int k = h; k < MDIM; k += 2) sc = fmaf(q[k], m[k], sc);
    sc += __shfl_xor(sc, 32);
    sc *= (1.0f / 16.0f);
    bool allowed = (CSZ * c + (CSZ - 1)) < s;
    float v = allowed ? sc : -3.4e38f;
    float mx = v;
    #pragma unroll
    for (int d = 16; d >= 1; d >>= 1) mx = fmaxf(mx, __shfl_xor(mx, d));
    float e = (allowed && mx > -1e37f) ? expf(sc - mx) : 0.f;
    float sm = e;
    #pragma unroll
    for (int d = 16; d >= 1; d >>= 1) sm += __shfl_xor(sm, d);
    float a = (sm > 0.f) ? e / sm : 0.f;
    if (lane < 32) attn[(size_t)s * NCHUNK + c] = a;
}

// ---------------------------------------------------------------------------
// total_partial = base_partial + attn @ chunk_partial; scatter-add into out
// ---------------------------------------------------------------------------
__global__ __launch_bounds__(256) void total_scatter_kernel(const float* __restrict__ bp,
                                                            const float* __restrict__ cp,
                                                            const float* __restrict__ attn,
                                                            const int* __restrict__ uids,
                                                            float* __restrict__ out) {
    int s = blockIdx.x;
    __shared__ float a_s[NCHUNK];
    if (threadIdx.x < NCHUNK) a_s[threadIdx.x] = attn[(size_t)s * NCHUNK + threadIdx.x];
    __syncthreads();
    for (int u = threadIdx.x; u < UDIM; u += 256) {
        float t = bp[(size_t)s * UDIM + u];
        #pragma unroll 8
        for (int c = 0; c < NCHUNK; c++)
            t = fmaf(a_s[c], cp[(size_t)c * UDIM + u], t);
        atomicAdd(&out[(size_t)s * VOC + uids[u]], t);
    }
}

// ---------------------------------------------------------------------------
// launch
// ---------------------------------------------------------------------------
extern "C" void kernel_launch(void* const* d_in, const int* in_sizes, int n_in,
                              void* d_out, int out_size, void* d_ws, size_t ws_size,
                              hipStream_t stream) {
    const int*   ids   = (const int*)d_in[0];
    const int*   uids  = (const int*)d_in[1];
    const float* emb   = (const float*)d_in[2];
    const float* w_ih  = (const float*)d_in[3];
    const float* w_hh  = (const float*)d_in[4];
    const float* b_ih  = (const float*)d_in[5];
    const float* b_hh  = (const float*)d_in[6];
    const float* Wq    = (const float*)d_in[7];
    const float* bq    = (const float*)d_in[8];
    const float* Wk    = (const float*)d_in[9];
    const float* bk    = (const float*)d_in[10];
    const float* Whf   = (const float*)d_in[11];
    const float* bhf   = (const float*)d_in[12];
    const float* Whp   = (const float*)d_in[13];
    const float* bhp   = (const float*)d_in[14];
    const float* Wcv   = (const float*)d_in[15];
    const float* bcv   = (const float*)d_in[16];
    const float* Wph   = (const float*)d_in[17];
    const float* bph   = (const float*)d_in[18];
    const float* obias = (const float*)d_in[19];
    float* out = (float*)d_out;
    float* wsf = (float*)d_ws;

    // workspace layout (floats)
    size_t off = 0;
    float* X      = wsf + off; off += (size_t)SEQ * EMB;
    float* GX     = wsf + off; off += (size_t)SEQ * G3;
    float* states = wsf + off; off += (size_t)SEQ * HID;
    float* head   = wsf + off; off += (size_t)SEQ * E4;
    float* bfeat  = wsf + off; off += (size_t)SEQ * EMB;
    float* chunk  = wsf + off; off += (size_t)NCHUNK * HID;
    float* qk     = wsf + off; off += (size_t)SEQ * MDIM;
    float* mk     = wsf + off; off += (size_t)NCHUNK * MDIM;
    float* cv     = wsf + off; off += (size_t)NCHUNK * EMB;
    float* cp     = wsf + off; off += (size_t)NCHUNK * UDIM;
    float* bp     = wsf + off; off += (size_t)SEQ * UDIM;
    float* attn   = wsf + off; off += (size_t)SEQ * NCHUNK;

    // 1) embedding gather; canary-fill states early (off critical path)
    embed_kernel<<<SEQ, 256, 0, stream>>>(ids, emb, X);
    hipMemsetAsync(states, 0xFF, (size_t)SEQ * HID * sizeof(float), stream);
    // 2) GX = X @ w_ih^T + b_ih
    gemm_nt<0><<<dim3(G3 / 128, SEQ / 128), 256, 0, stream>>>(X, w_ih, b_ih, GX, SEQ, G3, EMB);
    // 3) persistent GRU
    gru_kernel<<<G_GRU, 256, 0, stream>>>(GX, w_hh, b_hh, states);
    // 4) chunk means
    chunkmean_kernel<<<NCHUNK, 256, 0, stream>>>(states, chunk);
    // 5) projections (fp32)
    gemm_nt<0><<<dim3(MDIM / 128, SEQ / 128), 256, 0, stream>>>(states, Wq, bq, qk, SEQ, MDIM, HID);
    gemm_nt<0><<<dim3(MDIM / 128, 1), 256, 0, stream>>>(chunk, Wk, bk, mk, NCHUNK, MDIM, HID);
    gemm_nt<1><<<dim3(E4 / 128, SEQ / 128), 256, 0, stream>>>(states, Whf, bhf, head, SEQ, E4, HID);
    gemm_nt<0><<<dim3(EMB / 128, SEQ / 128), 256, 0, stream>>>(head, Whp, bhp, bfeat, SEQ, EMB, E4);
    gemm_nt<0><<<dim3(EMB / 128, 1), 256, 0, stream>>>(chunk, Wcv, bcv, cv, NCHUNK, EMB, HID);
    gemm_nt<0><<<dim3(UDIM / 128, 1), 256, 0, stream>>>(cv, Wph, bph, cp, NCHUNK, UDIM, EMB);
    gemm_nt<0><<<dim3(UDIM / 128, SEQ / 128), 256, 0, stream>>>(bfeat, Wph, bph, bp, SEQ, UDIM, EMB);
    // 6) base_logits (bf16 MFMA) -> d_out
    gemm_bf16_logits<<<dim3((VOC + 127) / 128, SEQ / 128), 256, 0, stream>>>(bfeat, emb, obias, out, SEQ, VOC, EMB);
    // 7) attention weights
    attn_kernel<<<SEQ, 64, 0, stream>>>(qk, mk, attn);
    // 8) total partial + scatter-add
    total_scatter_kernel<<<SEQ, 256, 0, stream>>>(bp, cp, attn, uids, out);
}

// Round 5
// 5171.609 us; speedup vs baseline: 1.6722x; 1.1107x over previous
//
#include <hip/hip_runtime.h>
#include <hip/hip_bf16.h>
#include <math.h>

// Problem constants
#define SEQ   2048
#define VOC   50257
#define EMB   512
#define HID   768
#define G3    2304      // 3*HID
#define MDIM  256
#define CSZ   64
#define NCHUNK 32
#define UDIM  2048
#define E4    2048      // 4*EMB

#define G_GRU 48
#define CANARY 0xFFFFFFFFu

typedef uint32_t u32x4  __attribute__((ext_vector_type(4)));
typedef float    f32x4  __attribute__((ext_vector_type(4)));
typedef short    s16x8  __attribute__((ext_vector_type(8)));   // 8 bf16 (4 VGPRs)
typedef __bf16   bf16x8 __attribute__((ext_vector_type(8)));

// ---------------------------------------------------------------------------
// fp32 -> bf16 convert (grid-stride, 8 elems/thread)
// ---------------------------------------------------------------------------
__global__ __launch_bounds__(256) void cvt_f32_bf16(const float* __restrict__ src,
                                                    __bf16* __restrict__ dst, int n8) {
    int stride = gridDim.x * 256;
    for (int i = blockIdx.x * 256 + threadIdx.x; i < n8; i += stride) {
        const float4* s = reinterpret_cast<const float4*>(src + (size_t)i * 8);
        float4 a = s[0], b = s[1];
        bf16x8 o;
        o[0]=(__bf16)a.x; o[1]=(__bf16)a.y; o[2]=(__bf16)a.z; o[3]=(__bf16)a.w;
        o[4]=(__bf16)b.x; o[5]=(__bf16)b.y; o[6]=(__bf16)b.z; o[7]=(__bf16)b.w;
        *reinterpret_cast<bf16x8*>(dst + (size_t)i * 8) = o;
    }
}

// ---------------------------------------------------------------------------
// Embedding gathers
// ---------------------------------------------------------------------------
__global__ __launch_bounds__(256) void embed_kernel(const int* __restrict__ ids,
                                                    const float* __restrict__ emb,
                                                    float* __restrict__ X) {
    int s = blockIdx.x;
    int id = ids[s];
    const float* src = &emb[(size_t)id * EMB];
    float* dst = &X[(size_t)s * EMB];
    for (int i = threadIdx.x; i < EMB; i += 256) dst[i] = src[i];
}

__global__ __launch_bounds__(64) void embed16_kernel(const int* __restrict__ ids,
                                                     const __bf16* __restrict__ emb16,
                                                     __bf16* __restrict__ X16) {
    int s = blockIdx.x;
    int id = ids[s];
    const bf16x8* src = reinterpret_cast<const bf16x8*>(emb16 + (size_t)id * EMB);
    bf16x8* dst = reinterpret_cast<bf16x8*>(X16 + (size_t)s * EMB);
    int i = threadIdx.x;              // EMB/8 == 64
    dst[i] = src[i];
}

// ---------------------------------------------------------------------------
// Generic fp32 GEMM:  C[M,N] = A[M,K] @ B[N,K]^T + bias[N]. EPI 1 = relu^2.
// ---------------------------------------------------------------------------
template<int EPI>
__global__ __launch_bounds__(256) void gemm_nt(const float* __restrict__ A,
                                               const float* __restrict__ B,
                                               const float* __restrict__ bias,
                                               float* __restrict__ C,
                                               int M, int N, int K) {
    __shared__ float As[16][132];
    __shared__ float Bs[16][132];
    const int tid = threadIdx.x;
    const int tx = tid & 15;
    const int ty = tid >> 4;
    const int m0 = blockIdx.y * 128;
    const int n0 = blockIdx.x * 128;

    float acc[8][8];
    #pragma unroll
    for (int i = 0; i < 8; i++)
        #pragma unroll
        for (int j = 0; j < 8; j++) acc[i][j] = 0.f;

    for (int k0 = 0; k0 < K; k0 += 16) {
        #pragma unroll
        for (int i = 0; i < 2; i++) {
            int idx = tid * 2 + i;
            int r   = idx >> 2;
            int c4  = idx & 3;
            float4 av = {0.f, 0.f, 0.f, 0.f};
            float4 bv = {0.f, 0.f, 0.f, 0.f};
            int ar = m0 + r;
            if (ar < M) av = *reinterpret_cast<const float4*>(&A[(size_t)ar * K + k0 + c4 * 4]);
            int br = n0 + r;
            if (br < N) bv = *reinterpret_cast<const float4*>(&B[(size_t)br * K + k0 + c4 * 4]);
            As[c4 * 4 + 0][r] = av.x; As[c4 * 4 + 1][r] = av.y;
            As[c4 * 4 + 2][r] = av.z; As[c4 * 4 + 3][r] = av.w;
            Bs[c4 * 4 + 0][r] = bv.x; Bs[c4 * 4 + 1][r] = bv.y;
            Bs[c4 * 4 + 2][r] = bv.z; Bs[c4 * 4 + 3][r] = bv.w;
        }
        __syncthreads();
        #pragma unroll
        for (int k = 0; k < 16; k++) {
            float4 a0 = *reinterpret_cast<const float4*>(&As[k][ty * 4]);
            float4 a1 = *reinterpret_cast<const float4*>(&As[k][64 + ty * 4]);
            float4 b0 = *reinterpret_cast<const float4*>(&Bs[k][tx * 4]);
            float4 b1 = *reinterpret_cast<const float4*>(&Bs[k][64 + tx * 4]);
            float a[8] = {a0.x, a0.y, a0.z, a0.w, a1.x, a1.y, a1.z, a1.w};
            float b[8] = {b0.x, b0.y, b0.z, b0.w, b1.x, b1.y, b1.z, b1.w};
            #pragma unroll
            for (int i = 0; i < 8; i++)
                #pragma unroll
                for (int j = 0; j < 8; j++)
                    acc[i][j] = fmaf(a[i], b[j], acc[i][j]);
        }
        __syncthreads();
    }

    #pragma unroll
    for (int i = 0; i < 8; i++) {
        int r = m0 + ((i < 4) ? (ty * 4 + i) : (64 + ty * 4 + (i - 4)));
        if (r >= M) continue;
        #pragma unroll
        for (int j = 0; j < 8; j++) {
            int c = n0 + ((j < 4) ? (tx * 4 + j) : (64 + tx * 4 + (j - 4)));
            if (c >= N) continue;
            float v = acc[i][j] + bias[c];
            if (EPI == 1) { v = fmaxf(v, 0.f); v = v * v; }
            C[(size_t)r * N + c] = v;
        }
    }
}

// ---------------------------------------------------------------------------
// bf16-input MFMA GEMM: C[M,N]fp32 = A[M,K]bf16 @ B[N,K]bf16^T + bias.
// 128x128x32 tiles, 4 waves (2x2 of 64x64), mfma_f32_16x16x32_bf16, LDT=40.
// M must be a multiple of 128; N guarded.
// ---------------------------------------------------------------------------
template<int EPI>
__global__ __launch_bounds__(256) void gemm_bt16(const __bf16* __restrict__ A,
                                                 const __bf16* __restrict__ B,
                                                 const float* __restrict__ bias,
                                                 float* __restrict__ C,
                                                 int M, int N, int K) {
    constexpr int LDT = 40;
    __shared__ __bf16 As[128 * LDT];
    __shared__ __bf16 Bs[128 * LDT];
    const int tid  = threadIdx.x;
    const int lane = tid & 63;
    const int wave = tid >> 6;
    const int wm = wave >> 1;
    const int wn = wave & 1;
    const int m0 = blockIdx.y * 128;
    const int n0 = blockIdx.x * 128;
    const int l15 = lane & 15;
    const int l4  = lane >> 4;

    f32x4 acc[4][4];
    #pragma unroll
    for (int i = 0; i < 4; i++)
        #pragma unroll
        for (int j = 0; j < 4; j++) acc[i][j] = (f32x4){0.f, 0.f, 0.f, 0.f};

    const int r  = tid >> 1;
    const int hf = tid & 1;

    for (int k0 = 0; k0 < K; k0 += 32) {
        const __bf16* ap = &A[(size_t)(m0 + r) * K + k0 + hf * 16];
        s16x8 av0 = *reinterpret_cast<const s16x8*>(ap);
        s16x8 av1 = *reinterpret_cast<const s16x8*>(ap + 8);
        s16x8 bv0, bv1;
        #pragma unroll
        for (int q = 0; q < 8; q++) { bv0[q] = 0; bv1[q] = 0; }
        int bn = n0 + r;
        if (bn < N) {
            const __bf16* bp = &B[(size_t)bn * K + k0 + hf * 16];
            bv0 = *reinterpret_cast<const s16x8*>(bp);
            bv1 = *reinterpret_cast<const s16x8*>(bp + 8);
        }
        __syncthreads();   // previous tile fully consumed
        *reinterpret_cast<s16x8*>(&As[r * LDT + hf * 16])     = av0;
        *reinterpret_cast<s16x8*>(&As[r * LDT + hf * 16 + 8]) = av1;
        *reinterpret_cast<s16x8*>(&Bs[r * LDT + hf * 16])     = bv0;
        *reinterpret_cast<s16x8*>(&Bs[r * LDT + hf * 16 + 8]) = bv1;
        __syncthreads();

        s16x8 af[4], bf[4];
        #pragma unroll
        for (int i = 0; i < 4; i++)
            af[i] = *reinterpret_cast<const s16x8*>(&As[(wm * 64 + i * 16 + l15) * LDT + l4 * 8]);
        #pragma unroll
        for (int j = 0; j < 4; j++)
            bf[j] = *reinterpret_cast<const s16x8*>(&Bs[(wn * 64 + j * 16 + l15) * LDT + l4 * 8]);
        #pragma unroll
        for (int i = 0; i < 4; i++)
            #pragma unroll
            for (int j = 0; j < 4; j++)
                acc[i][j] = __builtin_amdgcn_mfma_f32_16x16x32_bf16(af[i], bf[j], acc[i][j], 0, 0, 0);
    }

    #pragma unroll
    for (int j = 0; j < 4; j++) {
        int col = n0 + wn * 64 + j * 16 + l15;
        if (col >= N) continue;
        float bv = bias[col];
        #pragma unroll
        for (int i = 0; i < 4; i++) {
            int row = m0 + wm * 64 + i * 16 + l4 * 4;
            #pragma unroll
            for (int q = 0; q < 4; q++) {
                float v = acc[i][j][q] + bv;
                if (EPI == 1) { v = fmaxf(v, 0.f); v = v * v; }
                C[(size_t)(row + q) * N + col] = v;
            }
        }
    }
}

// ---------------------------------------------------------------------------
// fp32-input bf16 MFMA GEMM for base_logits (fallback path; verified r3/r4)
// ---------------------------------------------------------------------------
__global__ __launch_bounds__(256) void gemm_bf16_logits(const float* __restrict__ A,
                                                        const float* __restrict__ B,
                                                        const float* __restrict__ bias,
                                                        float* __restrict__ C,
                                                        int M, int N, int K) {
    constexpr int LDT = 40;
    __shared__ __bf16 As[128 * LDT];
    __shared__ __bf16 Bs[128 * LDT];
    const int tid  = threadIdx.x;
    const int lane = tid & 63;
    const int wave = tid >> 6;
    const int wm = wave >> 1;
    const int wn = wave & 1;
    const int m0 = blockIdx.y * 128;
    const int n0 = blockIdx.x * 128;
    const int l15 = lane & 15;
    const int l4  = lane >> 4;

    f32x4 acc[4][4];
    #pragma unroll
    for (int i = 0; i < 4; i++)
        #pragma unroll
        for (int j = 0; j < 4; j++) acc[i][j] = (f32x4){0.f, 0.f, 0.f, 0.f};

    const int r  = tid >> 1;
    const int hf = tid & 1;

    for (int k0 = 0; k0 < K; k0 += 32) {
        const float* ap = &A[(size_t)(m0 + r) * K + k0 + hf * 16];
        float4 a0 = *reinterpret_cast<const float4*>(ap);
        float4 a1 = *reinterpret_cast<const float4*>(ap + 4);
        float4 a2 = *reinterpret_cast<const float4*>(ap + 8);
        float4 a3 = *reinterpret_cast<const float4*>(ap + 12);
        int bn = n0 + r;
        float4 b0 = {0,0,0,0}, b1 = {0,0,0,0}, b2 = {0,0,0,0}, b3 = {0,0,0,0};
        if (bn < N) {
            const float* bp = &B[(size_t)bn * K + k0 + hf * 16];
            b0 = *reinterpret_cast<const float4*>(bp);
            b1 = *reinterpret_cast<const float4*>(bp + 4);
            b2 = *reinterpret_cast<const float4*>(bp + 8);
            b3 = *reinterpret_cast<const float4*>(bp + 12);
        }
        __syncthreads();
        {
            __bf16* da = &As[r * LDT + hf * 16];
            bf16x8 w0, w1;
            w0[0]=(__bf16)a0.x; w0[1]=(__bf16)a0.y; w0[2]=(__bf16)a0.z; w0[3]=(__bf16)a0.w;
            w0[4]=(__bf16)a1.x; w0[5]=(__bf16)a1.y; w0[6]=(__bf16)a1.z; w0[7]=(__bf16)a1.w;
            w1[0]=(__bf16)a2.x; w1[1]=(__bf16)a2.y; w1[2]=(__bf16)a2.z; w1[3]=(__bf16)a2.w;
            w1[4]=(__bf16)a3.x; w1[5]=(__bf16)a3.y; w1[6]=(__bf16)a3.z; w1[7]=(__bf16)a3.w;
            *reinterpret_cast<bf16x8*>(da)     = w0;
            *reinterpret_cast<bf16x8*>(da + 8) = w1;
            __bf16* db = &Bs[r * LDT + hf * 16];
            bf16x8 v0, v1;
            v0[0]=(__bf16)b0.x; v0[1]=(__bf16)b0.y; v0[2]=(__bf16)b0.z; v0[3]=(__bf16)b0.w;
            v0[4]=(__bf16)b1.x; v0[5]=(__bf16)b1.y; v0[6]=(__bf16)b1.z; v0[7]=(__bf16)b1.w;
            v1[0]=(__bf16)b2.x; v1[1]=(__bf16)b2.y; v1[2]=(__bf16)b2.z; v1[3]=(__bf16)b2.w;
            v1[4]=(__bf16)b3.x; v1[5]=(__bf16)b3.y; v1[6]=(__bf16)b3.z; v1[7]=(__bf16)b3.w;
            *reinterpret_cast<bf16x8*>(db)     = v0;
            *reinterpret_cast<bf16x8*>(db + 8) = v1;
        }
        __syncthreads();

        s16x8 af[4], bf[4];
        #pragma unroll
        for (int i = 0; i < 4; i++)
            af[i] = *reinterpret_cast<const s16x8*>(&As[(wm * 64 + i * 16 + l15) * LDT + l4 * 8]);
        #pragma unroll
        for (int j = 0; j < 4; j++)
            bf[j] = *reinterpret_cast<const s16x8*>(&Bs[(wn * 64 + j * 16 + l15) * LDT + l4 * 8]);
        #pragma unroll
        for (int i = 0; i < 4; i++)
            #pragma unroll
            for (int j = 0; j < 4; j++)
                acc[i][j] = __builtin_amdgcn_mfma_f32_16x16x32_bf16(af[i], bf[j], acc[i][j], 0, 0, 0);
    }

    #pragma unroll
    for (int j = 0; j < 4; j++) {
        int col = n0 + wn * 64 + j * 16 + l15;
        if (col >= N) continue;
        float bv = bias[col];
        #pragma unroll
        for (int i = 0; i < 4; i++) {
            int row = m0 + wm * 64 + i * 16 + l4 * 4;
            #pragma unroll
            for (int q = 0; q < 4; q++)
                C[(size_t)(row + q) * N + col] = acc[i][j][q] + bv;
        }
    }
}

// ---------------------------------------------------------------------------
// GRU v4 (unchanged from round 4; 3.86 ms verified)
// ---------------------------------------------------------------------------
__device__ __forceinline__ float fast_sigmoid(float x) {
    x = fminf(fmaxf(x, -30.f), 30.f);
    return __builtin_amdgcn_rcpf(1.f + __expf(-x));
}
__device__ __forceinline__ float fast_tanh(float x) {
    x = fminf(fmaxf(x, -15.f), 15.f);
    float e = __expf(2.f * x);
    return (e - 1.f) * __builtin_amdgcn_rcpf(e + 1.f);
}

__global__ __launch_bounds__(256, 1) void gru_kernel(const float* __restrict__ GX,
                                                     const float* __restrict__ Whh,
                                                     const float* __restrict__ bhh,
                                                     float* __restrict__ states) {
    __shared__ float h_s[HID];
    const int tid  = threadIdx.x;
    const int g    = blockIdx.x;
    const int tx   = tid & 15;
    const int ty   = tid >> 4;
    const int gu   = g * 16 + ty;
    const int wave = tid >> 6;
    const int lane = tid & 63;

    float4 W4[3][12];
    #pragma unroll
    for (int p = 0; p < 3; p++) {
        const float* wr = &Whh[(size_t)(p * HID + gu) * HID + 4 * tx];
        #pragma unroll
        for (int j = 0; j < 12; j++)
            W4[p][j] = *reinterpret_cast<const float4*>(&wr[64 * j]);
    }
    float bh[3];
    #pragma unroll
    for (int p = 0; p < 3; p++) bh[p] = bhh[p * HID + gu];

    float hv  = 0.f;
    float gx0 = GX[0 * HID + gu];
    float gx1 = GX[1 * HID + gu];
    float gx2 = GX[2 * HID + gu];

    for (int t = 0; t < SEQ; t++) {
        float ngx0 = 0.f, ngx1 = 0.f, ngx2 = 0.f;
        if (t + 1 < SEQ) {
            const float* gp = &GX[(size_t)(t + 1) * G3];
            ngx0 = gp[0 * HID + gu];
            ngx1 = gp[1 * HID + gu];
            ngx2 = gp[2 * HID + gu];
        }

        float4 h4[12];
        if (t > 0) {
            if (tid < 192) {
                const float* pp = states + (size_t)(t - 1) * HID + tid * 4;
                u32x4 q;
                float s;
                do {
                    asm volatile(
                        "global_load_dwordx4 %0, %1, off sc0 sc1\n\t"
                        "s_waitcnt vmcnt(0)"
                        : "=&v"(q) : "v"(pp) : "memory");
                    f32x4 f = __builtin_bit_cast(f32x4, q);
                    s = f[0] + f[1] + f[2] + f[3];
                } while (s != s);
                *reinterpret_cast<u32x4*>(&h_s[tid * 4]) = q;
            }
            __syncthreads();
            #pragma unroll
            for (int j = 0; j < 12; j++)
                h4[j] = *reinterpret_cast<const float4*>(&h_s[4 * tx + 64 * j]);
        } else {
            #pragma unroll
            for (int j = 0; j < 12; j++) h4[j] = make_float4(0.f, 0.f, 0.f, 0.f);
        }

        float accp[3];
        #pragma unroll
        for (int p = 0; p < 3; p++) {
            float a = 0.f;
            #pragma unroll
            for (int j = 0; j < 12; j++) {
                a = fmaf(W4[p][j].x, h4[j].x, a);
                a = fmaf(W4[p][j].y, h4[j].y, a);
                a = fmaf(W4[p][j].z, h4[j].z, a);
                a = fmaf(W4[p][j].w, h4[j].w, a);
            }
            accp[p] = a;
        }
        #pragma unroll
        for (int p = 0; p < 3; p++) {
            accp[p] += __shfl_xor(accp[p], 1);
            accp[p] += __shfl_xor(accp[p], 2);
            accp[p] += __shfl_xor(accp[p], 4);
            accp[p] += __shfl_xor(accp[p], 8);
        }

        float r = fast_sigmoid(gx0 + accp[0] + bh[0]);
        float z = fast_sigmoid(gx1 + accp[1] + bh[1]);
        float n = fast_tanh(gx2 + r * (accp[2] + bh[2]));
        hv = (1.f - z) * n + z * hv;

        float v0 = __shfl(hv, 0);
        float v1 = __shfl(hv, 16);
        float v2 = __shfl(hv, 32);
        float v3 = __shfl(hv, 48);
        if (lane == 0) {
            f32x4 pv = {v0, v1, v2, v3};
            float* dp = states + (size_t)t * HID + g * 16 + wave * 4;
            asm volatile(
                "global_store_dwordx4 %0, %1, off sc0 sc1"
                :: "v"(dp), "v"(pv) : "memory");
        }
        gx0 = ngx0; gx1 = ngx1; gx2 = ngx2;
    }
}

// ---------------------------------------------------------------------------
// chunk means / attention / scatter (unchanged)
// ---------------------------------------------------------------------------
__global__ __launch_bounds__(256) void chunkmean_kernel(const float* __restrict__ states,
                                                        float* __restrict__ chunked) {
    int c = blockIdx.x;
    for (int e = threadIdx.x; e < HID; e += 256) {
        float s = 0.f;
        #pragma unroll 8
        for (int i = 0; i < CSZ; i++)
            s += states[(size_t)(c * CSZ + i) * HID + e];
        chunked[c * HID + e] = s * (1.f / 64.f);
    }
}

__global__ void attn_kernel(const float* __restrict__ qk,
                            const float* __restrict__ mk,
                            float* __restrict__ attn) {
    int s = blockIdx.x;
    int lane = threadIdx.x;
    int c = lane & 31;
    int h = lane >> 5;
    const float* q = &qk[(size_t)s * MDIM];
    const float* m = &mk[(size_t)c * MDIM];
    float sc = 0.f;
    for (int k = h; k < MDIM; k += 2) sc = fmaf(q[k], m[k], sc);
    sc += __shfl_xor(sc, 32);
    sc *= (1.0f / 16.0f);
    bool allowed = (CSZ * c + (CSZ - 1)) < s;
    float v = allowed ? sc : -3.4e38f;
    float mx = v;
    #pragma unroll
    for (int d = 16; d >= 1; d >>= 1) mx = fmaxf(mx, __shfl_xor(mx, d));
    float e = (allowed && mx > -1e37f) ? expf(sc - mx) : 0.f;
    float sm = e;
    #pragma unroll
    for (int d = 16; d >= 1; d >>= 1) sm += __shfl_xor(sm, d);
    float a = (sm > 0.f) ? e / sm : 0.f;
    if (lane < 32) attn[(size_t)s * NCHUNK + c] = a;
}

__global__ __launch_bounds__(256) void total_scatter_kernel(const float* __restrict__ bp,
                                                            const float* __restrict__ cp,
                                                            const float* __restrict__ attn,
                                                            const int* __restrict__ uids,
                                                            float* __restrict__ out) {
    int s = blockIdx.x;
    __shared__ float a_s[NCHUNK];
    if (threadIdx.x < NCHUNK) a_s[threadIdx.x] = attn[(size_t)s * NCHUNK + threadIdx.x];
    __syncthreads();
    for (int u = threadIdx.x; u < UDIM; u += 256) {
        float t = bp[(size_t)s * UDIM + u];
        #pragma unroll 8
        for (int c = 0; c < NCHUNK; c++)
            t = fmaf(a_s[c], cp[(size_t)c * UDIM + u], t);
        atomicAdd(&out[(size_t)s * VOC + uids[u]], t);
    }
}

// ---------------------------------------------------------------------------
// launch
// ---------------------------------------------------------------------------
static inline int cvt_grid(int n8) {
    int g = (n8 + 255) / 256;
    return g > 2048 ? 2048 : g;
}

extern "C" void kernel_launch(void* const* d_in, const int* in_sizes, int n_in,
                              void* d_out, int out_size, void* d_ws, size_t ws_size,
                              hipStream_t stream) {
    const int*   ids   = (const int*)d_in[0];
    const int*   uids  = (const int*)d_in[1];
    const float* emb   = (const float*)d_in[2];
    const float* w_ih  = (const float*)d_in[3];
    const float* w_hh  = (const float*)d_in[4];
    const float* b_ih  = (const float*)d_in[5];
    const float* b_hh  = (const float*)d_in[6];
    const float* Wq    = (const float*)d_in[7];
    const float* bq    = (const float*)d_in[8];
    const float* Wk    = (const float*)d_in[9];
    const float* bk    = (const float*)d_in[10];
    const float* Whf   = (const float*)d_in[11];
    const float* bhf   = (const float*)d_in[12];
    const float* Whp   = (const float*)d_in[13];
    const float* bhp   = (const float*)d_in[14];
    const float* Wcv   = (const float*)d_in[15];
    const float* bcv   = (const float*)d_in[16];
    const float* Wph   = (const float*)d_in[17];
    const float* bph   = (const float*)d_in[18];
    const float* obias = (const float*)d_in[19];
    float* out = (float*)d_out;
    float* wsf = (float*)d_ws;

    // common workspace (floats)
    size_t off = 0;
    float* GX     = wsf + off; off += (size_t)SEQ * G3;
    float* states = wsf + off; off += (size_t)SEQ * HID;
    float* head   = wsf + off; off += (size_t)SEQ * E4;
    float* bfeat  = wsf + off; off += (size_t)SEQ * EMB;
    float* chunk  = wsf + off; off += (size_t)NCHUNK * HID;
    float* qk     = wsf + off; off += (size_t)SEQ * MDIM;
    float* mk     = wsf + off; off += (size_t)NCHUNK * MDIM;
    float* cv     = wsf + off; off += (size_t)NCHUNK * EMB;
    float* cp     = wsf + off; off += (size_t)NCHUNK * UDIM;
    float* bp     = wsf + off; off += (size_t)SEQ * UDIM;
    float* attn   = wsf + off; off += (size_t)SEQ * NCHUNK;
    size_t common_off = off;

    // big-path extras (bf16 arrays, counted in float units = count/2)
    __bf16* X16     = (__bf16*)(wsf + off); off += (size_t)SEQ * EMB / 2;
    __bf16* emb16   = (__bf16*)(wsf + off); off += (size_t)VOC * EMB / 2;
    __bf16* wih16   = (__bf16*)(wsf + off); off += (size_t)G3 * EMB / 2;
    __bf16* Whp16   = (__bf16*)(wsf + off); off += (size_t)EMB * E4 / 2;
    __bf16* Wph16   = (__bf16*)(wsf + off); off += (size_t)UDIM * EMB / 2;
    __bf16* head16  = (__bf16*)(wsf + off); off += (size_t)SEQ * E4 / 2;
    __bf16* bfeat16 = (__bf16*)(wsf + off); off += (size_t)SEQ * EMB / 2;
    const bool big = ws_size >= off * sizeof(float);

    if (big) {
        // 0) one-time-per-call bf16 conversions (off GRU critical path except emb/wih)
        cvt_f32_bf16<<<cvt_grid(VOC * EMB / 8), 256, 0, stream>>>(emb, emb16, VOC * EMB / 8);
        cvt_f32_bf16<<<cvt_grid(G3 * EMB / 8), 256, 0, stream>>>(w_ih, wih16, G3 * EMB / 8);
        cvt_f32_bf16<<<cvt_grid(EMB * E4 / 8), 256, 0, stream>>>(Whp, Whp16, EMB * E4 / 8);
        cvt_f32_bf16<<<cvt_grid(UDIM * EMB / 8), 256, 0, stream>>>(Wph, Wph16, UDIM * EMB / 8);
        // 1) gather + canary fill
        embed16_kernel<<<SEQ, 64, 0, stream>>>(ids, emb16, X16);
        hipMemsetAsync(states, 0xFF, (size_t)SEQ * HID * sizeof(float), stream);
        // 2) GX (bf16 MFMA)
        gemm_bt16<0><<<dim3(G3 / 128, SEQ / 128), 256, 0, stream>>>(X16, wih16, b_ih, GX, SEQ, G3, EMB);
        // 3) GRU
        gru_kernel<<<G_GRU, 256, 0, stream>>>(GX, w_hh, b_hh, states);
        // 4) chunk means + small fp32 projections
        chunkmean_kernel<<<NCHUNK, 256, 0, stream>>>(states, chunk);
        gemm_nt<0><<<dim3(MDIM / 128, SEQ / 128), 256, 0, stream>>>(states, Wq, bq, qk, SEQ, MDIM, HID);
        gemm_nt<0><<<dim3(MDIM / 128, 1), 256, 0, stream>>>(chunk, Wk, bk, mk, NCHUNK, MDIM, HID);
        // 5) head (fp32 for accuracy: relu^2 amplifies input rounding)
        gemm_nt<1><<<dim3(E4 / 128, SEQ / 128), 256, 0, stream>>>(states, Whf, bhf, head, SEQ, E4, HID);
        cvt_f32_bf16<<<cvt_grid(SEQ * E4 / 8), 256, 0, stream>>>(head, head16, SEQ * E4 / 8);
        // 6) bfeat = head @ Whp^T (bf16 MFMA), then bf16 copy
        gemm_bt16<0><<<dim3(EMB / 128, SEQ / 128), 256, 0, stream>>>(head16, Whp16, bhp, bfeat, SEQ, EMB, E4);
        cvt_f32_bf16<<<cvt_grid(SEQ * EMB / 8), 256, 0, stream>>>(bfeat, bfeat16, SEQ * EMB / 8);
        // 7) small chunk-value chain (fp32, tiny)
        gemm_nt<0><<<dim3(EMB / 128, 1), 256, 0, stream>>>(chunk, Wcv, bcv, cv, NCHUNK, EMB, HID);
        gemm_nt<0><<<dim3(UDIM / 128, 1), 256, 0, stream>>>(cv, Wph, bph, cp, NCHUNK, UDIM, EMB);
        // 8) bp (bf16 MFMA)
        gemm_bt16<0><<<dim3(UDIM / 128, SEQ / 128), 256, 0, stream>>>(bfeat16, Wph16, bph, bp, SEQ, UDIM, EMB);
        // 9) base_logits (pure-bf16 MFMA) -> d_out
        gemm_bt16<0><<<dim3((VOC + 127) / 128, SEQ / 128), 256, 0, stream>>>(bfeat16, emb16, obias, out, SEQ, VOC, EMB);
        // 10) attention + scatter
        attn_kernel<<<SEQ, 64, 0, stream>>>(qk, mk, attn);
        total_scatter_kernel<<<SEQ, 256, 0, stream>>>(bp, cp, attn, uids, out);
    } else {
        // fallback: round-4 path (fp32 GEMMs + fp32-input logits MFMA)
        float* X = wsf + common_off;   // reuse extras region
        embed_kernel<<<SEQ, 256, 0, stream>>>(ids, emb, X);
        hipMemsetAsync(states, 0xFF, (size_t)SEQ * HID * sizeof(float), stream);
        gemm_nt<0><<<dim3(G3 / 128, SEQ / 128), 256, 0, stream>>>(X, w_ih, b_ih, GX, SEQ, G3, EMB);
        gru_kernel<<<G_GRU, 256, 0, stream>>>(GX, w_hh, b_hh, states);
        chunkmean_kernel<<<NCHUNK, 256, 0, stream>>>(states, chunk);
        gemm_nt<0><<<dim3(MDIM / 128, SEQ / 128), 256, 0, stream>>>(states, Wq, bq, qk, SEQ, MDIM, HID);
        gemm_nt<0><<<dim3(MDIM / 128, 1), 256, 0, stream>>>(chunk, Wk, bk, mk, NCHUNK, MDIM, HID);
        gemm_nt<1><<<dim3(E4 / 128, SEQ / 128), 256, 0, stream>>>(states, Whf, bhf, head, SEQ, E4, HID);
        gemm_nt<0><<<dim3(EMB / 128, SEQ / 128), 256, 0, stream>>>(head, Whp, bhp, bfeat, SEQ, EMB, E4);
        gemm_nt<0><<<dim3(EMB / 128, 1), 256, 0, stream>>>(chunk, Wcv, bcv, cv, NCHUNK, EMB, HID);
        gemm_nt<0><<<dim3(UDIM / 128, 1), 256, 0, stream>>>(cv, Wph, bph, cp, NCHUNK, UDIM, EMB);
        gemm_nt<0><<<dim3(UDIM / 128, SEQ / 128), 256, 0, stream>>>(bfeat, Wph, bph, bp, SEQ, UDIM, EMB);
        gemm_bf16_logits<<<dim3((VOC + 127) / 128, SEQ / 128), 256, 0, stream>>>(bfeat, emb, obias, out, SEQ, VOC, EMB);
        attn_kernel<<<SEQ, 64, 0, stream>>>(qk, mk, attn);
        total_scatter_kernel<<<SEQ, 256, 0, stream>>>(bp, cp, attn, uids, out);
    }
}